// Round 1
// baseline (40248.770 us; speedup 1.0000x reference)
//
#include <hip/hip_runtime.h>
#include <hip/hip_bf16.h>
#include <cstdint>
#include <cstddef>

// ---------------------------------------------------------------------------
// ConditionalSmilesRnn: 3-layer LSTM, H=1024, B=256, T=128, greedy decode.
// Round 1: correctness-first fp32 implementation.
//   - per step: 3x fused GEMM+LSTM-cell kernels + 1 decode/argmax/embed kernel
//   - activations stored transposed [K][256] so A-tile staging is linear
//   - weights read in original layout, register-staged + transposed into LDS
// ---------------------------------------------------------------------------

#define H 1024
#define BB 256
#define TT 128
#define OO 47

// workspace layout (in floats)
#define XC0   0                      // [2080][256]  emb(1024) | props(4) | h0(1024) | pad(28)
#define XC1   532480                 // [2048][256]  h0 | h1
#define XC2   1056768                // [2048][256]  h1 | h2
#define CBUF  1581056                // [3][256][1024]
#define H2N   2367488                // [256][1024]  h2 natural layout
#define BCOMB 2629632                // [3][4096]
#define WS_FLOATS 2641920

__device__ __forceinline__ float fsig(float x) {
  return 1.0f / (1.0f + exp2f(-1.4426950408889634f * x));
}
__device__ __forceinline__ float ftanhf(float x) {
  float e = exp2f(2.8853900817779268f * x);   // e^(2x)
  return 1.0f - 2.0f / (e + 1.0f);
}

__device__ __forceinline__ void gload_lds16(const float* g, float* l) {
  __builtin_amdgcn_global_load_lds(
      (const __attribute__((address_space(1))) unsigned int*)g,
      (__attribute__((address_space(3))) unsigned int*)l, 16, 0, 0);
}

// ---------------------------------------------------------------------------
__global__ void k_zero(float* ws, int n) {
  int i = blockIdx.x * blockDim.x + threadIdx.x;
  int stride = gridDim.x * blockDim.x;
  for (; i < n; i += stride) ws[i] = 0.0f;
}

__global__ void k_init(float* ws, const float* __restrict__ props,
                       const float* __restrict__ emb,
                       const float* __restrict__ bih,
                       const float* __restrict__ bhh) {
  int i = blockIdx.x * blockDim.x + threadIdx.x;
  if (i < 262144) {                       // xc0 rows 0..1023 = emb[token 0]^T
    int h = i >> 8, b = i & 255;
    ws[XC0 + h * 256 + b] = emb[h];
  } else if (i < 262144 + 1024) {         // xc0 rows 1024..1027 = properties^T
    int j = i - 262144;
    int p = j >> 8, b = j & 255;
    ws[XC0 + (1024 + p) * 256 + b] = props[b * 4 + p];
  } else if (i < 262144 + 1024 + 12288) { // combined biases
    int j = i - 263168;
    ws[BCOMB + j] = bih[j] + bhh[j];
  }
}

// ---------------------------------------------------------------------------
// Fused GEMM ([256 x 4096] = A^T-slices dot W rows) + LSTM cell.
// Grid: 256 blocks (4 batch-tiles x 64 h-tiles), 256 threads.
__global__ __launch_bounds__(256) void k_layer(
    const float* __restrict__ xc,    // [Kpad][256] activations (transposed)
    const float* __restrict__ Wx, int wx_stride,
    const float* __restrict__ Wh,    // stride 1024
    const float* __restrict__ bcomb, // [4096]
    float* __restrict__ cbuf,        // [256][1024]
    float* __restrict__ hselfT,      // xc + K1*256
    float* __restrict__ hnextT,      // next layer's xc rows 0.. (or null)
    float* __restrict__ hnat,        // natural [256][1024] (or null)
    int K1, int Kact, int Kpad) {
  __shared__ float Alds[2][32][64];
  __shared__ float Blds[2][32][64];
  __shared__ float Glds[64][68];
  __shared__ float Hlds[16][68];

  const int tid = threadIdx.x;
  const int wave = tid >> 6, lane = tid & 63;
  const int mt = blockIdx.x & 3, nt = blockIdx.x >> 2;
  const int m0 = mt * 64, h0 = nt * 16;
  const int cg = tid & 15, rg = tid >> 4;

  // B staging: thread -> (n_loc = tid>>2, k4 = tid&3); 2 float4 granules along K
  const int n_loc = tid >> 2;
  const int k4 = tid & 3;
  const int gsec = n_loc >> 4, hh_b = n_loc & 15;
  const int nrow = gsec * 1024 + h0 + hh_b;   // global gate-row in W
  const float* wxrow = Wx + (size_t)nrow * wx_stride;
  const float* whrow = Wh + (size_t)nrow * 1024;

  float acc[4][4] = {{0.f}};
  float breg[2][4];

  const int nst = Kpad >> 5;

  auto stageA = [&](int s, int buf) {
#pragma unroll
    for (int i = 0; i < 2; ++i) {
      int krb = wave * 8 + i * 4;
      const float* g4 = xc + (size_t)((s << 5) + krb + (lane >> 4)) * 256 + m0 + (lane & 15) * 4;
      gload_lds16(g4, &Alds[buf][krb][0]);
    }
  };
  auto stageB_load = [&](int s) {
    int k0 = s << 5;
#pragma unroll
    for (int q = 0; q < 2; ++q) {
      int kk = k0 + (k4 + q * 4) * 4;
      float4 v = {0.f, 0.f, 0.f, 0.f};
      if (kk < Kact) {
        const float* src = (kk < K1) ? (wxrow + kk) : (whrow + (kk - K1));
        v = *(const float4*)src;
      }
      breg[q][0] = v.x; breg[q][1] = v.y; breg[q][2] = v.z; breg[q][3] = v.w;
    }
  };
  auto stageB_write = [&](int buf) {
#pragma unroll
    for (int q = 0; q < 2; ++q) {
      int kl = (k4 + q * 4) * 4;
#pragma unroll
      for (int j = 0; j < 4; ++j) Blds[buf][kl + j][n_loc] = breg[q][j];
    }
  };

  // prologue
  stageA(0, 0);
  stageB_load(0);
  stageB_write(0);
  __syncthreads();

  for (int s = 0; s < nst; ++s) {
    const int cur = s & 1, nxt = cur ^ 1;
    const bool more = (s + 1 < nst);
    if (more) { stageA(s + 1, nxt); stageB_load(s + 1); }
#pragma unroll
    for (int k = 0; k < 32; ++k) {
      float4 a4 = *(const float4*)&Alds[cur][k][rg * 4];
      float4 b4 = *(const float4*)&Blds[cur][k][cg * 4];
      const float av[4] = {a4.x, a4.y, a4.z, a4.w};
      const float bv[4] = {b4.x, b4.y, b4.z, b4.w};
#pragma unroll
      for (int i = 0; i < 4; ++i)
#pragma unroll
        for (int j = 0; j < 4; ++j) acc[i][j] += av[i] * bv[j];
    }
    if (more) stageB_write(nxt);
    __syncthreads();
  }

  // gate exchange through LDS
#pragma unroll
  for (int i = 0; i < 4; ++i) {
    float4 v = {acc[i][0], acc[i][1], acc[i][2], acc[i][3]};
    *(float4*)&Glds[rg * 4 + i][cg * 4] = v;
  }
  __syncthreads();

  // cell update: thread -> (hh = tid&15, 4 batch rows)
  const int hh = tid & 15, rgc = tid >> 4;
  const int hcol = h0 + hh;
  const float bI = bcomb[hcol];
  const float bF = bcomb[1024 + hcol];
  const float bG = bcomb[2048 + hcol];
  const float bO = bcomb[3072 + hcol];
#pragma unroll
  for (int i = 0; i < 4; ++i) {
    int bl = rgc * 4 + i;
    int b = m0 + bl;
    float xi = Glds[bl][hh] + bI;
    float xf = Glds[bl][16 + hh] + bF;
    float xg = Glds[bl][32 + hh] + bG;
    float xo = Glds[bl][48 + hh] + bO;
    size_t cidx = (size_t)b * 1024 + hcol;
    float cn = fsig(xf) * cbuf[cidx] + fsig(xi) * ftanhf(xg);
    float hn = fsig(xo) * ftanhf(cn);
    cbuf[cidx] = cn;
    if (hnat) hnat[cidx] = hn;
    Hlds[hh][bl] = hn;
  }
  __syncthreads();

  // transposed, coalesced h write-out
  const int hw = tid >> 4, bq = (tid & 15) * 4;
  float4 hv = *(const float4*)&Hlds[hw][bq];
  size_t off = (size_t)(h0 + hw) * 256 + m0 + bq;
  *(float4*)&hselfT[off] = hv;
  if (hnextT) *(float4*)&hnextT[off] = hv;
}

// ---------------------------------------------------------------------------
// decode: logits = h2 @ W_dec^T + b_dec; greedy argmax; write emb^T for next step
__global__ __launch_bounds__(64) void k_decode(
    const float* __restrict__ h2, const float* __restrict__ Wdec,
    const float* __restrict__ bdec, const float* __restrict__ emb,
    float* __restrict__ out, float* __restrict__ xc0, int t) {
  const int b = blockIdx.x, lane = threadIdx.x;
  float logit = 0.f;
  if (lane < OO) {
    const float* wrow = Wdec + (size_t)lane * 1024;
    const float* hrow = h2 + (size_t)b * 1024;
    float p0 = 0.f, p1 = 0.f, p2 = 0.f, p3 = 0.f;
    for (int k = 0; k < 1024; k += 16) {
      float4 w0 = *(const float4*)(wrow + k);      float4 h0v = *(const float4*)(hrow + k);
      float4 w1 = *(const float4*)(wrow + k + 4);  float4 h1v = *(const float4*)(hrow + k + 4);
      float4 w2 = *(const float4*)(wrow + k + 8);  float4 h2v = *(const float4*)(hrow + k + 8);
      float4 w3 = *(const float4*)(wrow + k + 12); float4 h3v = *(const float4*)(hrow + k + 12);
      p0 += w0.x * h0v.x + w0.y * h0v.y + w0.z * h0v.z + w0.w * h0v.w;
      p1 += w1.x * h1v.x + w1.y * h1v.y + w1.z * h1v.z + w1.w * h1v.w;
      p2 += w2.x * h2v.x + w2.y * h2v.y + w2.z * h2v.z + w2.w * h2v.w;
      p3 += w3.x * h3v.x + w3.y * h3v.y + w3.z * h3v.z + w3.w * h3v.w;
    }
    logit = ((p0 + p1) + (p2 + p3)) + bdec[lane];
  }
  float v = (lane < OO) ? logit : -3.0e38f;
  int idx = (lane < OO) ? lane : 1000;
#pragma unroll
  for (int m = 1; m < 64; m <<= 1) {
    float v2 = __shfl_xor(v, m, 64);
    int i2 = __shfl_xor(idx, m, 64);
    if (v2 > v || (v2 == v && i2 < idx)) { v = v2; idx = i2; }
  }
  if (lane < OO) out[(size_t)b * (TT * OO) + t * OO + lane] = logit;
  if (t < TT - 1) {
    const float* erow = emb + (size_t)idx * 1024;
#pragma unroll
    for (int i = 0; i < 16; ++i) {
      int h = i * 64 + lane;
      xc0[h * 256 + b] = erow[h];
    }
  }
}

// ---------------------------------------------------------------------------
__global__ void k_final(const float* __restrict__ ws, float* __restrict__ out) {
  int i = blockIdx.x * blockDim.x + threadIdx.x;
  int stride = gridDim.x * blockDim.x;
  const int HBASE = BB * TT * OO;          // 1540096
  for (; i < 2 * 786432; i += stride) {
    if (i < 786432) {  // h: [L][B][H] from transposed xcat rows
      int l = i >> 18, r = i & 262143, b = r >> 10, j = r & 1023;
      size_t xb = (l == 0) ? (size_t)XC0 : (l == 1) ? (size_t)XC1 : (size_t)XC2;
      int k1 = (l == 0) ? 1028 : 1024;
      out[HBASE + i] = ws[xb + (size_t)(k1 + j) * 256 + b];
    } else {           // c: direct copy
      int j = i - 786432;
      out[HBASE + 786432 + j] = ws[CBUF + j];
    }
  }
}

// ---------------------------------------------------------------------------
extern "C" void kernel_launch(void* const* d_in, const int* in_sizes, int n_in,
                              void* d_out, int out_size, void* d_ws, size_t ws_size,
                              hipStream_t stream) {
  const float* props = (const float*)d_in[1];
  const float* emb   = (const float*)d_in[2];
  const float* Wdec  = (const float*)d_in[3];
  const float* bdec  = (const float*)d_in[4];
  const float* Wih0  = (const float*)d_in[5];
  const float* Wihr  = (const float*)d_in[6];
  const float* Whh   = (const float*)d_in[7];
  const float* bih   = (const float*)d_in[8];
  const float* bhh   = (const float*)d_in[9];

  float* ws  = (float*)d_ws;
  float* out = (float*)d_out;

  float* xc0 = ws + XC0;
  float* xc1 = ws + XC1;
  float* xc2 = ws + XC2;
  float* cb  = ws + CBUF;
  float* h2n = ws + H2N;
  float* bc  = ws + BCOMB;

  k_zero<<<2048, 256, 0, stream>>>(ws, 2629632);
  k_init<<<1076, 256, 0, stream>>>(ws, props, emb, bih, bhh);

  for (int t = 0; t < TT; ++t) {
    // layer 0: K = 1028 (emb+props) + 1024 (h0), padded to 2080
    k_layer<<<256, 256, 0, stream>>>(xc0, Wih0, 1028, Whh, bc, cb,
                                     xc0 + 1028 * 256, xc1, nullptr,
                                     1028, 2052, 2080);
    // layer 1
    k_layer<<<256, 256, 0, stream>>>(xc1, Wihr, 1024, Whh + (size_t)4096 * 1024,
                                     bc + 4096, cb + 262144,
                                     xc1 + 1024 * 256, xc2, nullptr,
                                     1024, 2048, 2048);
    // layer 2 (also writes natural-layout h2 for decode)
    k_layer<<<256, 256, 0, stream>>>(xc2, Wihr + (size_t)4096 * 1024, 1024,
                                     Whh + (size_t)2 * 4096 * 1024,
                                     bc + 2 * 4096, cb + 2 * 262144,
                                     xc2 + 1024 * 256, nullptr, h2n,
                                     1024, 2048, 2048);
    k_decode<<<256, 64, 0, stream>>>(h2n, Wdec, bdec, emb, out, xc0, t);
  }
  k_final<<<2048, 256, 0, stream>>>(ws, out);
}

// Round 4
// 21180.362 us; speedup vs baseline: 1.9003x; 1.9003x over previous
//
#include <hip/hip_runtime.h>
#include <hip/hip_bf16.h>
#include <cstdint>
#include <cstddef>

// ---------------------------------------------------------------------------
// ConditionalSmilesRnn: 3-layer LSTM, H=1024, B=256, T=128, greedy decode.
// Round 4: fp16x3 split MFMA GEMM + PING-PONG h buffers (fixes the
// intra-kernel h read/write race that poisoned R2/R3's c output).
//   a = hi + lo/2048 (lo prescaled by 2048; residual ~2^-22)
//   gates = (accH0+accH1) + (accL0+accL1)/2048
// ---------------------------------------------------------------------------

#define BB 256
#define TT 128
#define OO 47

// workspace layout (float offsets)
#define EBUF  0           // [256][1056]: emb(1024)|props(4)|pad(28) — L0 x-input
#define HPB   270336      // [3][2][256][1024] h ping-pong
#define CBUF  1843200     // [3][256][1024]
#define BCOMB 2629632     // [3][4096]
#define WS_N  2641920
#define HP_OFF(l, p) (HPB + ((l) * 2 + (p)) * 262144)

typedef __attribute__((ext_vector_type(8))) _Float16 f16x8;
typedef __attribute__((ext_vector_type(4))) float f32x4;

__device__ __forceinline__ float fsig(float x) {
  return 1.0f / (1.0f + exp2f(-1.4426950408889634f * x));
}
__device__ __forceinline__ float ftanhf(float x) {
  float e = exp2f(2.8853900817779268f * x);
  return 1.0f - 2.0f / (e + 1.0f);
}

// ---------------------------------------------------------------------------
__global__ void k_zero(float* ws, int n) {
  int i = blockIdx.x * blockDim.x + threadIdx.x;
  int stride = gridDim.x * blockDim.x;
  for (; i < n; i += stride) ws[i] = 0.0f;
}

__global__ void k_init(float* ws, const float* __restrict__ props,
                       const float* __restrict__ emb,
                       const float* __restrict__ bih,
                       const float* __restrict__ bhh) {
  int i = blockIdx.x * blockDim.x + threadIdx.x;
  if (i < 270336) {                       // E[b][j]
    int b = i / 1056, j = i % 1056;
    float v = 0.0f;
    if (j < 1024) v = emb[j];             // token 0 embedding
    else if (j < 1028) v = props[b * 4 + (j - 1024)];
    ws[EBUF + i] = v;
  } else if (i < 270336 + 12288) {        // combined biases
    int j = i - 270336;
    ws[BCOMB + j] = bih[j] + bhh[j];
  }
}

// ---------------------------------------------------------------------------
// fp16x3 MFMA fused GEMM+LSTM-cell. grid 256 (4 batch x 64 h tiles,
// XCD-swizzled), 512 threads (8 waves).
// waves 0-3: x-part (xsrc vs Wx); waves 4-7: h-part (hsrc vs Wh).
// LDS: [buf2][A/B][half2][hi/lo] 4KB fragment-linear slabs = 64 KB.
__global__ __launch_bounds__(512, 2) void k_layer(
    const float* __restrict__ xsrc, int xs, int Kx, int nst0,
    const float* __restrict__ hsrc,
    const float* __restrict__ Wx, int wxs,
    const float* __restrict__ Wh,
    const float* __restrict__ bcomb, float* __restrict__ cbuf,
    float* __restrict__ hdst) {
  __shared__ char LBUF[65536];
  const int tid = threadIdx.x;
  const int lane = tid & 63, wid = tid >> 6;
  const int sw = ((blockIdx.x & 7) << 5) + (blockIdx.x >> 3);  // XCD swizzle
  const int mt = sw & 3, nt = sw >> 2;
  const int m0 = mt << 6;    // batch tile base
  const int h0c = nt << 4;   // h-unit tile base
  const int nstMax = (nst0 > 32) ? nst0 : 32;

  // ---- staging role: 4 groups of 128 threads, one 64x32 fp32 tile each ----
  const int tile = tid >> 7;           // 0:A-x 1:A-h 2:B-x 3:B-h
  const int tt = tid & 127;
  const int srow = tt >> 1;            // 0..63 (m or n row)
  const int kseg = (tt & 1) << 4;      // 0 or 16 (k within 32-chunk)
  const int isB = tile >> 1, sHalf = tile & 1;
  const int myNst = sHalf ? 32 : nst0;
  const float* grow;
  int KactB = 0x7fffffff;
  if (!isB) {
    grow = sHalf ? (hsrc + (size_t)(m0 + srow) * 1024)
                 : (xsrc + (size_t)(m0 + srow) * xs);
  } else {
    int nrow = ((srow >> 4) << 10) + h0c + (srow & 15);  // gate-interleaved row
    grow = sHalf ? (Wh + (size_t)nrow * 1024) : (Wx + (size_t)nrow * wxs);
    KactB = sHalf ? 1024 : Kx;
  }
  // LDS write base within a 4KB slab region: [rowblk][kgrp2][row][8elem]*2B
  const int wbase = ((srow >> 4) << 10) + ((tt & 1) << 9) + ((srow & 15) << 4);
  const int ssec = (isB << 14) + (sHalf << 13);

  // ---- compute role ----
  const int wHalf = wid >> 2, q = wid & 3;
  const int mb = (q >> 1) << 1;    // A slab base (x1KB)
  const int nbb = (q & 1) << 1;    // B slab base
  const int waveNst = wHalf ? 32 : nst0;
  const int secAr = (wHalf << 13);
  const int secBr = 16384 + (wHalf << 13);

  f32x4 accH[4], accL[4];
#pragma unroll
  for (int i = 0; i < 4; ++i) {
    accH[i] = f32x4{0.f, 0.f, 0.f, 0.f};
    accL[i] = f32x4{0.f, 0.f, 0.f, 0.f};
  }

  float4 v[4];
  auto load_regs = [&](int s) {
    const int kl = (s << 5) + kseg;
    const float4* p = (const float4*)(grow + kl);
#pragma unroll
    for (int qq = 0; qq < 4; ++qq) {
      int kk = kl + qq * 4;
      if (kk < KactB) v[qq] = p[qq];
      else v[qq] = float4{0.f, 0.f, 0.f, 0.f};
    }
  };
  auto cvt_write = [&](int buf) {
    char* base = LBUF + buf * 32768 + ssec + wbase;
#pragma unroll
    for (int g = 0; g < 2; ++g) {
      float fs[8] = {v[2*g].x, v[2*g].y, v[2*g].z, v[2*g].w,
                     v[2*g+1].x, v[2*g+1].y, v[2*g+1].z, v[2*g+1].w};
      f16x8 hvv, lvv;
#pragma unroll
      for (int j = 0; j < 8; ++j) {
        _Float16 h16 = (_Float16)fs[j];                      // RNE
        float fhi = (float)h16;
        lvv[j] = (_Float16)((fs[j] - fhi) * 2048.0f);        // scaled lo
        hvv[j] = h16;
      }
      *(f16x8*)(base + g * 256) = hvv;
      *(f16x8*)(base + g * 256 + 4096) = lvv;
    }
  };

  load_regs(0);
  cvt_write(0);
  __syncthreads();

  for (int s = 0; s < nstMax; ++s) {
    const int cur = s & 1, nxt = cur ^ 1;
    const bool doStage = (s + 1 < myNst);
    if (doStage) load_regs(s + 1);

    if (s < waveNst) {
      const char* A0 = LBUF + cur * 32768 + secAr;
      const char* B0 = LBUF + cur * 32768 + secBr;
      f16x8 ah[2], al[2], bh[2], bl[2];
#pragma unroll
      for (int r = 0; r < 2; ++r) {
        ah[r] = *(const f16x8*)(A0 + ((mb + r) << 10) + (lane << 4));
        al[r] = *(const f16x8*)(A0 + 4096 + ((mb + r) << 10) + (lane << 4));
      }
#pragma unroll
      for (int c = 0; c < 2; ++c) {
        bh[c] = *(const f16x8*)(B0 + ((nbb + c) << 10) + (lane << 4));
        bl[c] = *(const f16x8*)(B0 + 4096 + ((nbb + c) << 10) + (lane << 4));
      }
#pragma unroll
      for (int r = 0; r < 2; ++r)
#pragma unroll
        for (int c = 0; c < 2; ++c) {
          int ix = r * 2 + c;
          accH[ix] = __builtin_amdgcn_mfma_f32_16x16x32_f16(ah[r], bh[c], accH[ix], 0, 0, 0);
          accL[ix] = __builtin_amdgcn_mfma_f32_16x16x32_f16(al[r], bh[c], accL[ix], 0, 0, 0);
          accL[ix] = __builtin_amdgcn_mfma_f32_16x16x32_f16(ah[r], bl[c], accL[ix], 0, 0, 0);
        }
    }

    if (doStage) cvt_write(nxt);
    __syncthreads();
  }

  // ---- epilogue: combine halves (hi and lo sums separately), fused cell ----
  float* GH = (float*)LBUF;            // [64][68]
  float* GL = GH + 64 * 68;            // [64][68]
  const int mrow0 = ((q >> 1) << 5) + ((lane >> 4) << 2);
  const int ncol0 = ((q & 1) << 5) + (lane & 15);
  if (wHalf == 0) {
#pragma unroll
    for (int r = 0; r < 2; ++r)
#pragma unroll
      for (int c = 0; c < 2; ++c) {
        f32x4 aH = accH[r * 2 + c], aL = accL[r * 2 + c];
        int mr = mrow0 + r * 16, nc = ncol0 + c * 16;
#pragma unroll
        for (int i = 0; i < 4; ++i) {
          GH[(mr + i) * 68 + nc] = aH[i];
          GL[(mr + i) * 68 + nc] = aL[i];
        }
      }
  }
  __syncthreads();
  if (wHalf == 1) {
#pragma unroll
    for (int r = 0; r < 2; ++r)
#pragma unroll
      for (int c = 0; c < 2; ++c) {
        f32x4 aH = accH[r * 2 + c], aL = accL[r * 2 + c];
        int mr = mrow0 + r * 16, nc = ncol0 + c * 16;
#pragma unroll
        for (int i = 0; i < 4; ++i) {
          GH[(mr + i) * 68 + nc] += aH[i];
          GL[(mr + i) * 68 + nc] += aL[i];
        }
      }
  }
  __syncthreads();

  const float LSC = 1.0f / 2048.0f;
#pragma unroll
  for (int e = 0; e < 2; ++e) {
    int ci = tid * 2 + e;           // 0..1023
    int bl_ = ci >> 4, hh = ci & 15;
    int b = m0 + bl_, hcol = h0c + hh;
    float xi = GH[bl_ * 68 + hh]      + GL[bl_ * 68 + hh]      * LSC + bcomb[hcol];
    float xf = GH[bl_ * 68 + 16 + hh] + GL[bl_ * 68 + 16 + hh] * LSC + bcomb[1024 + hcol];
    float xg = GH[bl_ * 68 + 32 + hh] + GL[bl_ * 68 + 32 + hh] * LSC + bcomb[2048 + hcol];
    float xo = GH[bl_ * 68 + 48 + hh] + GL[bl_ * 68 + 48 + hh] * LSC + bcomb[3072 + hcol];
    size_t cidx = (size_t)b * 1024 + hcol;
    float cn = fsig(xf) * cbuf[cidx] + fsig(xi) * ftanhf(xg);
    float hn = fsig(xo) * ftanhf(cn);
    cbuf[cidx] = cn;
    hdst[cidx] = hn;
  }
}

// ---------------------------------------------------------------------------
// decode: logits = h2 @ W_dec^T + b_dec; greedy argmax; write next emb into E
__global__ __launch_bounds__(64) void k_decode(
    const float* __restrict__ h2, const float* __restrict__ Wdec,
    const float* __restrict__ bdec, const float* __restrict__ emb,
    float* __restrict__ out, float* __restrict__ ebuf, int t) {
  const int b = blockIdx.x, lane = threadIdx.x;
  const float* hrow = h2 + (size_t)b * 1024;
  float logit = 0.f;
  if (lane < OO) {
    const float* wrow = Wdec + (size_t)lane * 1024;
    float p0 = 0.f, p1 = 0.f, p2 = 0.f, p3 = 0.f;
    for (int k = 0; k < 1024; k += 16) {
      float4 w0 = *(const float4*)(wrow + k);      float4 h0v = *(const float4*)(hrow + k);
      float4 w1 = *(const float4*)(wrow + k + 4);  float4 h1v = *(const float4*)(hrow + k + 4);
      float4 w2 = *(const float4*)(wrow + k + 8);  float4 h2v = *(const float4*)(hrow + k + 8);
      float4 w3 = *(const float4*)(wrow + k + 12); float4 h3v = *(const float4*)(hrow + k + 12);
      p0 += w0.x * h0v.x + w0.y * h0v.y + w0.z * h0v.z + w0.w * h0v.w;
      p1 += w1.x * h1v.x + w1.y * h1v.y + w1.z * h1v.z + w1.w * h1v.w;
      p2 += w2.x * h2v.x + w2.y * h2v.y + w2.z * h2v.z + w2.w * h2v.w;
      p3 += w3.x * h3v.x + w3.y * h3v.y + w3.z * h3v.z + w3.w * h3v.w;
    }
    logit = ((p0 + p1) + (p2 + p3)) + bdec[lane];
  }
  float vv = (lane < OO) ? logit : -3.0e38f;
  int idx = (lane < OO) ? lane : 1000;
#pragma unroll
  for (int m = 1; m < 64; m <<= 1) {
    float v2 = __shfl_xor(vv, m, 64);
    int i2 = __shfl_xor(idx, m, 64);
    if (v2 > vv || (v2 == vv && i2 < idx)) { vv = v2; idx = i2; }
  }
  if (lane < OO) out[(size_t)b * (TT * OO) + t * OO + lane] = logit;
  if (t < TT - 1) {
    const float* erow = emb + (size_t)idx * 1024;
#pragma unroll
    for (int i = 0; i < 16; ++i) {
      int h = i * 64 + lane;
      ebuf[(size_t)b * 1056 + h] = erow[h];
    }
  }
}

// ---------------------------------------------------------------------------
__global__ void k_final(const float* __restrict__ ws, float* __restrict__ out) {
  int i = blockIdx.x * blockDim.x + threadIdx.x;
  int stride = gridDim.x * blockDim.x;
  const int HBASE = BB * TT * OO;   // 1540096
  for (; i < 2 * 786432; i += stride) {
    if (i < 786432) {   // h [L][B][H]: final state lives in parity 0
      int l = i >> 18, r = i & 262143;
      out[HBASE + i] = ws[HP_OFF(l, 0) + r];
    } else {            // c [L][B][H]
      int j = i - 786432;
      out[HBASE + 786432 + j] = ws[CBUF + j];
    }
  }
}

// ---------------------------------------------------------------------------
extern "C" void kernel_launch(void* const* d_in, const int* in_sizes, int n_in,
                              void* d_out, int out_size, void* d_ws, size_t ws_size,
                              hipStream_t stream) {
  const float* props = (const float*)d_in[1];
  const float* emb   = (const float*)d_in[2];
  const float* Wdec  = (const float*)d_in[3];
  const float* bdec  = (const float*)d_in[4];
  const float* Wih0  = (const float*)d_in[5];
  const float* Wihr  = (const float*)d_in[6];
  const float* Whh   = (const float*)d_in[7];
  const float* bih   = (const float*)d_in[8];
  const float* bhh   = (const float*)d_in[9];

  float* ws  = (float*)d_ws;
  float* out = (float*)d_out;

  float* E  = ws + EBUF;
  float* cb = ws + CBUF;
  float* bc = ws + BCOMB;

  k_zero<<<2048, 256, 0, stream>>>(ws, WS_N);
  k_init<<<1104, 256, 0, stream>>>(ws, props, emb, bih, bhh);

  for (int t = 0; t < TT; ++t) {
    const int p = t & 1;
    // layer 0: x-part K=1028 (33 chunks, pad cols zero), h ping-pong
    k_layer<<<256, 512, 0, stream>>>(E, 1056, 1028, 33,
                                     ws + HP_OFF(0, p),
                                     Wih0, 1028, Whh,
                                     bc, cb, ws + HP_OFF(0, p ^ 1));
    // layer 1
    k_layer<<<256, 512, 0, stream>>>(ws + HP_OFF(0, p ^ 1), 1024, 1024, 32,
                                     ws + HP_OFF(1, p),
                                     Wihr, 1024, Whh + (size_t)4096 * 1024,
                                     bc + 4096, cb + 262144, ws + HP_OFF(1, p ^ 1));
    // layer 2
    k_layer<<<256, 512, 0, stream>>>(ws + HP_OFF(1, p ^ 1), 1024, 1024, 32,
                                     ws + HP_OFF(2, p),
                                     Wihr + (size_t)4096 * 1024, 1024,
                                     Whh + (size_t)2 * 4096 * 1024,
                                     bc + 8192, cb + 524288, ws + HP_OFF(2, p ^ 1));
    k_decode<<<256, 64, 0, stream>>>(ws + HP_OFF(2, p ^ 1), Wdec, bdec, emb,
                                     out, E, t);
  }
  k_final<<<2048, 256, 0, stream>>>(ws, out);
}

// Round 5
// 11202.195 us; speedup vs baseline: 3.5929x; 1.8907x over previous
//
#include <hip/hip_runtime.h>
#include <hip/hip_bf16.h>
#include <cstdint>
#include <cstddef>

// ---------------------------------------------------------------------------
// ConditionalSmilesRnn: 3-layer LSTM, H=1024, B=256, T=128, greedy decode.
// Round 5: fp16x3 split MFMA GEMM with PRE-SPLIT, PRE-SWIZZLED operands.
//   - weights split once (f16 hi + lo*2048) into LDS-slab-ordered buffers
//   - h/x producers (epilogue, decode) emit split slabs directly
//   - K-loop: global_load_lds slab copies + ds_read_b128 + 12 MFMA, no VALU
//   - ping-pong h buffers (race fix from R4) retained
//   - host falls back to R4 path if ws_size too small
// ---------------------------------------------------------------------------

#define BB 256
#define TT 128
#define OO 47

typedef __attribute__((ext_vector_type(8))) _Float16 f16x8;
typedef __attribute__((ext_vector_type(4))) float f32x4;

// ---- new-path workspace byte offsets ----
#define CBUF_B   0u                    // [3][256][1024] f32
#define HF32_B   3145728u              // [3][2][256][1024] f32
#define BCOMB_B  9437184u              // [3][4096] f32
#define EHI_B    9486336u              // [16][33][512] f16 slabs
#define ELO_B    10027008u
#define HS_B     10567680u             // [3][2][2]: 16*32*1024 B each
#define W_B      16859136u
#define WS_NEEDED 118046720u

__device__ __forceinline__ float fsig(float x) {
  return 1.0f / (1.0f + exp2f(-1.4426950408889634f * x));
}
__device__ __forceinline__ float ftanhf(float x) {
  float e = exp2f(2.8853900817779268f * x);
  return 1.0f - 2.0f / (e + 1.0f);
}
__device__ __forceinline__ unsigned short f16b(_Float16 h) {
  union { _Float16 f; unsigned short u; } c; c.f = h; return c.u;
}
__device__ __forceinline__ void gld16(const void* g, void* l) {
  __builtin_amdgcn_global_load_lds(
      (const __attribute__((address_space(1))) unsigned int*)g,
      (__attribute__((address_space(3))) unsigned int*)l, 16, 0, 0);
}
// slab address (in f16 units) for element (row-in-16-group r, k) of group grp
__device__ __forceinline__ size_t slab_addr(int grp, int NCH, int k, int r) {
  return ((size_t)grp * NCH + (k >> 5)) * 512 + ((k >> 4) & 1) * 256 +
         ((k >> 3) & 1) * 128 + r * 8 + (k & 7);
}

// ---------------------------------------------------------------------------
__global__ void k_zero(float* p, int n) {
  int i = blockIdx.x * blockDim.x + threadIdx.x;
  int stride = gridDim.x * blockDim.x;
  for (; i < n; i += stride) p[i] = 0.0f;
}

__global__ void k_binit(float* bc, const float* __restrict__ bih,
                        const float* __restrict__ bhh) {
  int i = blockIdx.x * blockDim.x + threadIdx.x;
  if (i < 12288) bc[i] = bih[i] + bhh[i];
}

// split fp32 weight matrix [4096][K] into slab-ordered f16 hi/lo (zero pad)
__global__ void k_prepw(const float* __restrict__ src, unsigned short* dhi,
                        unsigned short* dlo, int K, int NCH) {
  const int nrow = blockIdx.x;
  const int ngrp = nrow >> 4, rr = nrow & 15;
  const float* s = src + (size_t)nrow * K;
  for (int k = threadIdx.x; k < NCH * 32; k += blockDim.x) {
    float val = (k < K) ? s[k] : 0.0f;
    _Float16 h16 = (_Float16)val;
    _Float16 l16 = (_Float16)((val - (float)h16) * 2048.0f);
    size_t a = slab_addr(ngrp, NCH, k, rr);
    dhi[a] = f16b(h16);
    dlo[a] = f16b(l16);
  }
}

// E = [emb(tok 0) | props | pad] split into slabs (NCH=33)
__global__ void k_einit(unsigned short* ehi, unsigned short* elo,
                        const float* __restrict__ emb,
                        const float* __restrict__ props) {
  const int b = blockIdx.x;
  for (int j = threadIdx.x; j < 1056; j += blockDim.x) {
    float val = (j < 1024) ? emb[j] : (j < 1028 ? props[b * 4 + (j - 1024)] : 0.0f);
    _Float16 h16 = (_Float16)val;
    _Float16 l16 = (_Float16)((val - (float)h16) * 2048.0f);
    size_t a = slab_addr(b >> 4, 33, j, b & 15);
    ehi[a] = f16b(h16);
    elo[a] = f16b(l16);
  }
}

// ---------------------------------------------------------------------------
// fp16x3 MFMA fused GEMM+LSTM cell, pre-split operands.
// grid 256 (4 batch x 64 h tiles, XCD-swizzled), 512 threads (8 waves).
// LDS buffer (32KB): [isB][half][prec][slab4][1024B]; double-buffered.
// Staging: wave w -> isB=w>>2, half=(w>>1)&1, prec=w&1, 4 slab copies/chunk.
// Compute: wave w -> wHalf=w>>2, quadrant q=w&3 (32x32 of the 64x64 tile).
__global__ __launch_bounds__(512, 2) void k_layer(
    const char* __restrict__ xhi, const char* __restrict__ xlo, int NCHX,
    const char* __restrict__ hhi, const char* __restrict__ hlo,
    const char* __restrict__ wxhi, const char* __restrict__ wxlo,
    const char* __restrict__ whhi, const char* __restrict__ whlo,
    const float* __restrict__ bcomb, float* __restrict__ cbuf,
    float* __restrict__ hdstf, unsigned short* __restrict__ hshi,
    unsigned short* __restrict__ hslo) {
  __shared__ char LBUF[65536];
  const int tid = threadIdx.x;
  const int lane = tid & 63, wid = tid >> 6;
  const int sw = ((blockIdx.x & 7) << 5) + (blockIdx.x >> 3);  // XCD swizzle
  const int mt = sw & 3, nt = sw >> 2;
  const int m0 = mt << 6, h0c = nt << 4;
  const int nst = (NCHX > 32) ? NCHX : 32;

  // ---- staging role ----
  const int sIsB = wid >> 2, sHalfW = (wid >> 1) & 1, sPrec = wid & 1;
  const int sNch = sHalfW ? 32 : NCHX;
  const char* sbase[4];
  {
    const char* t0;
    if (!sIsB) t0 = sHalfW ? (sPrec ? hlo : hhi) : (sPrec ? xlo : xhi);
    else       t0 = sHalfW ? (sPrec ? whlo : whhi) : (sPrec ? wxlo : wxhi);
#pragma unroll
    for (int i = 0; i < 4; ++i) {
      int grp = sIsB ? (i * 64 + nt) : (mt * 4 + i);
      sbase[i] = t0 + (size_t)grp * sNch * 1024 + (size_t)lane * 16;
    }
  }
  const int ldsoff0 = (sIsB << 14) + (sHalfW << 13) + (sPrec << 12);
  auto stage = [&](int s, int buf) {
    char* ldst = LBUF + buf * 32768 + ldsoff0;
    const size_t so = (size_t)s * 1024;
#pragma unroll
    for (int i = 0; i < 4; ++i) gld16(sbase[i] + so, ldst + i * 1024);
  };

  // ---- compute role ----
  const int wHalf = wid >> 2, q = wid & 3;
  const int mb = (q >> 1) << 1, nbb = (q & 1) << 1;
  const int waveNst = wHalf ? 32 : NCHX;

  f32x4 accH[4], accL[4];
#pragma unroll
  for (int i = 0; i < 4; ++i) {
    accH[i] = f32x4{0.f, 0.f, 0.f, 0.f};
    accL[i] = f32x4{0.f, 0.f, 0.f, 0.f};
  }

  stage(0, 0);
  __syncthreads();

  for (int s = 0; s < nst; ++s) {
    const int cur = s & 1, nxt = cur ^ 1;
    if (s + 1 < sNch) stage(s + 1, nxt);

    if (s < waveNst) {
      const char* A0 = LBUF + cur * 32768 + (wHalf << 13);
      const char* B0 = LBUF + cur * 32768 + 16384 + (wHalf << 13);
      f16x8 ah[2], al[2], bh[2], bl[2];
#pragma unroll
      for (int r = 0; r < 2; ++r) {
        ah[r] = *(const f16x8*)(A0 + ((mb + r) << 10) + (lane << 4));
        al[r] = *(const f16x8*)(A0 + 4096 + ((mb + r) << 10) + (lane << 4));
      }
#pragma unroll
      for (int c = 0; c < 2; ++c) {
        bh[c] = *(const f16x8*)(B0 + ((nbb + c) << 10) + (lane << 4));
        bl[c] = *(const f16x8*)(B0 + 4096 + ((nbb + c) << 10) + (lane << 4));
      }
#pragma unroll
      for (int r = 0; r < 2; ++r)
#pragma unroll
        for (int c = 0; c < 2; ++c) {
          int ix = r * 2 + c;
          accH[ix] = __builtin_amdgcn_mfma_f32_16x16x32_f16(ah[r], bh[c], accH[ix], 0, 0, 0);
          accL[ix] = __builtin_amdgcn_mfma_f32_16x16x32_f16(al[r], bh[c], accL[ix], 0, 0, 0);
          accL[ix] = __builtin_amdgcn_mfma_f32_16x16x32_f16(ah[r], bl[c], accL[ix], 0, 0, 0);
        }
    }
    __syncthreads();
  }

  // ---- epilogue: combine halves, fused LSTM cell, split h emit ----
  float* GH = (float*)LBUF;            // [64][68]
  float* GL = GH + 64 * 68;
  const int mrow0 = ((q >> 1) << 5) + ((lane >> 4) << 2);
  const int ncol0 = ((q & 1) << 5) + (lane & 15);
  if (wHalf == 0) {
#pragma unroll
    for (int r = 0; r < 2; ++r)
#pragma unroll
      for (int c = 0; c < 2; ++c) {
        f32x4 aH = accH[r * 2 + c], aL = accL[r * 2 + c];
        int mr = mrow0 + r * 16, nc = ncol0 + c * 16;
#pragma unroll
        for (int i = 0; i < 4; ++i) {
          GH[(mr + i) * 68 + nc] = aH[i];
          GL[(mr + i) * 68 + nc] = aL[i];
        }
      }
  }
  __syncthreads();
  if (wHalf == 1) {
#pragma unroll
    for (int r = 0; r < 2; ++r)
#pragma unroll
      for (int c = 0; c < 2; ++c) {
        f32x4 aH = accH[r * 2 + c], aL = accL[r * 2 + c];
        int mr = mrow0 + r * 16, nc = ncol0 + c * 16;
#pragma unroll
        for (int i = 0; i < 4; ++i) {
          GH[(mr + i) * 68 + nc] += aH[i];
          GL[(mr + i) * 68 + nc] += aL[i];
        }
      }
  }
  __syncthreads();

  const float LSC = 1.0f / 2048.0f;
#pragma unroll
  for (int e = 0; e < 2; ++e) {
    int ci = tid * 2 + e;           // 0..1023
    int bl_ = ci >> 4, hh = ci & 15;
    int b = m0 + bl_, hcol = h0c + hh;
    float xi = GH[bl_ * 68 + hh]      + GL[bl_ * 68 + hh]      * LSC + bcomb[hcol];
    float xf = GH[bl_ * 68 + 16 + hh] + GL[bl_ * 68 + 16 + hh] * LSC + bcomb[1024 + hcol];
    float xg = GH[bl_ * 68 + 32 + hh] + GL[bl_ * 68 + 32 + hh] * LSC + bcomb[2048 + hcol];
    float xo = GH[bl_ * 68 + 48 + hh] + GL[bl_ * 68 + 48 + hh] * LSC + bcomb[3072 + hcol];
    size_t cidx = (size_t)b * 1024 + hcol;
    float cn = fsig(xf) * cbuf[cidx] + fsig(xi) * ftanhf(xg);
    float hn = fsig(xo) * ftanhf(cn);
    cbuf[cidx] = cn;
    hdstf[cidx] = hn;
    _Float16 h16 = (_Float16)hn;
    _Float16 l16 = (_Float16)((hn - (float)h16) * 2048.0f);
    size_t sa = slab_addr(b >> 4, 32, hcol, b & 15);
    hshi[sa] = f16b(h16);
    hslo[sa] = f16b(l16);
  }
}

// ---------------------------------------------------------------------------
// decode: 4-wave k-split dot, argmax, emit next-token emb into E slabs
__global__ __launch_bounds__(256) void k_decode(
    const float* __restrict__ h2, const float* __restrict__ Wdec,
    const float* __restrict__ bdec, const float* __restrict__ emb,
    float* __restrict__ out, unsigned short* __restrict__ ehi,
    unsigned short* __restrict__ elo, int t) {
  __shared__ float P[4][64];
  __shared__ int tokS;
  const int b = blockIdx.x;
  const int w = threadIdx.x >> 6, lane = threadIdx.x & 63;
  const float* hrow = h2 + (size_t)b * 1024 + w * 256;
  float part = 0.f;
  if (lane < OO) {
    const float* wrow = Wdec + (size_t)lane * 1024 + w * 256;
    float p0 = 0.f, p1 = 0.f, p2 = 0.f, p3 = 0.f;
    for (int k = 0; k < 256; k += 16) {
      float4 w0 = *(const float4*)(wrow + k);      float4 h0v = *(const float4*)(hrow + k);
      float4 w1 = *(const float4*)(wrow + k + 4);  float4 h1v = *(const float4*)(hrow + k + 4);
      float4 w2 = *(const float4*)(wrow + k + 8);  float4 h2v = *(const float4*)(hrow + k + 8);
      float4 w3 = *(const float4*)(wrow + k + 12); float4 h3v = *(const float4*)(hrow + k + 12);
      p0 += w0.x * h0v.x + w0.y * h0v.y + w0.z * h0v.z + w0.w * h0v.w;
      p1 += w1.x * h1v.x + w1.y * h1v.y + w1.z * h1v.z + w1.w * h1v.w;
      p2 += w2.x * h2v.x + w2.y * h2v.y + w2.z * h2v.z + w2.w * h2v.w;
      p3 += w3.x * h3v.x + w3.y * h3v.y + w3.z * h3v.z + w3.w * h3v.w;
    }
    part = (p0 + p1) + (p2 + p3);
  }
  P[w][lane] = part;
  __syncthreads();
  if (w == 0) {
    float logit = -3.0e38f;
    if (lane < OO)
      logit = P[0][lane] + P[1][lane] + P[2][lane] + P[3][lane] + bdec[lane];
    float vv = logit;
    int idx = (lane < OO) ? lane : 1000;
#pragma unroll
    for (int m = 1; m < 64; m <<= 1) {
      float v2 = __shfl_xor(vv, m, 64);
      int i2 = __shfl_xor(idx, m, 64);
      if (v2 > vv || (v2 == vv && i2 < idx)) { vv = v2; idx = i2; }
    }
    if (lane < OO) out[(size_t)b * (TT * OO) + t * OO + lane] = logit;
    if (lane == 0) tokS = idx;
  }
  __syncthreads();
  if (t < TT - 1) {
    const float* erow = emb + (size_t)tokS * 1024;
    float4 ev = ((const float4*)erow)[threadIdx.x];
    float vals[4] = {ev.x, ev.y, ev.z, ev.w};
#pragma unroll
    for (int r = 0; r < 4; ++r) {
      int j = threadIdx.x * 4 + r;
      _Float16 h16 = (_Float16)vals[r];
      _Float16 l16 = (_Float16)((vals[r] - (float)h16) * 2048.0f);
      size_t a = slab_addr(b >> 4, 33, j, b & 15);
      ehi[a] = f16b(h16);
      elo[a] = f16b(l16);
    }
  }
}

// ---------------------------------------------------------------------------
__global__ void k_final(const float* __restrict__ hf, const float* __restrict__ cb,
                        float* __restrict__ out) {
  int i = blockIdx.x * blockDim.x + threadIdx.x;
  int stride = gridDim.x * blockDim.x;
  const int HBASE = BB * TT * OO;   // 1540096
  for (; i < 2 * 786432; i += stride) {
    if (i < 786432) {               // h [L][B][H]; final state in parity 0
      int l = i >> 18, r = i & 262143;
      out[HBASE + i] = hf[(size_t)(l * 2 + 0) * 262144 + r];
    } else {
      int j = i - 786432;
      out[HBASE + 786432 + j] = cb[j];
    }
  }
}

// ===========================================================================
// ==================== LEGACY (R4) FALLBACK PATH ============================
// ===========================================================================
#define O_EBUF  0
#define O_HPB   270336
#define O_CBUF  1843200
#define O_BCOMB 2629632
#define O_WSN   2641920
#define O_HP(l, p) (O_HPB + ((l) * 2 + (p)) * 262144)

__global__ void k_initO(float* ws, const float* __restrict__ props,
                        const float* __restrict__ emb,
                        const float* __restrict__ bih,
                        const float* __restrict__ bhh) {
  int i = blockIdx.x * blockDim.x + threadIdx.x;
  if (i < 270336) {
    int b = i / 1056, j = i % 1056;
    float v = 0.0f;
    if (j < 1024) v = emb[j];
    else if (j < 1028) v = props[b * 4 + (j - 1024)];
    ws[O_EBUF + i] = v;
  } else if (i < 270336 + 12288) {
    int j = i - 270336;
    ws[O_BCOMB + j] = bih[j] + bhh[j];
  }
}

__global__ __launch_bounds__(512, 2) void k_layerO(
    const float* __restrict__ xsrc, int xs, int Kx, int nst0,
    const float* __restrict__ hsrc,
    const float* __restrict__ Wx, int wxs,
    const float* __restrict__ Wh,
    const float* __restrict__ bcomb, float* __restrict__ cbuf,
    float* __restrict__ hdst) {
  __shared__ char LBUF[65536];
  const int tid = threadIdx.x;
  const int lane = tid & 63, wid = tid >> 6;
  const int sw = ((blockIdx.x & 7) << 5) + (blockIdx.x >> 3);
  const int mt = sw & 3, nt = sw >> 2;
  const int m0 = mt << 6, h0c = nt << 4;
  const int nstMax = (nst0 > 32) ? nst0 : 32;
  const int tile = tid >> 7;
  const int tt = tid & 127;
  const int srow = tt >> 1;
  const int kseg = (tt & 1) << 4;
  const int isB = tile >> 1, sHalf = tile & 1;
  const int myNst = sHalf ? 32 : nst0;
  const float* grow;
  int KactB = 0x7fffffff;
  if (!isB) {
    grow = sHalf ? (hsrc + (size_t)(m0 + srow) * 1024)
                 : (xsrc + (size_t)(m0 + srow) * xs);
  } else {
    int nrow = ((srow >> 4) << 10) + h0c + (srow & 15);
    grow = sHalf ? (Wh + (size_t)nrow * 1024) : (Wx + (size_t)nrow * wxs);
    KactB = sHalf ? 1024 : Kx;
  }
  const int wbase = ((srow >> 4) << 10) + ((tt & 1) << 9) + ((srow & 15) << 4);
  const int ssec = (isB << 14) + (sHalf << 13);
  const int wHalf = wid >> 2, q = wid & 3;
  const int mb = (q >> 1) << 1, nbb = (q & 1) << 1;
  const int waveNst = wHalf ? 32 : nst0;
  const int secAr = (wHalf << 13);
  const int secBr = 16384 + (wHalf << 13);
  f32x4 accH[4], accL[4];
#pragma unroll
  for (int i = 0; i < 4; ++i) {
    accH[i] = f32x4{0.f, 0.f, 0.f, 0.f};
    accL[i] = f32x4{0.f, 0.f, 0.f, 0.f};
  }
  float4 v[4];
  auto load_regs = [&](int s) {
    const int kl = (s << 5) + kseg;
    const float4* p = (const float4*)(grow + kl);
#pragma unroll
    for (int qq = 0; qq < 4; ++qq) {
      int kk = kl + qq * 4;
      if (kk < KactB) v[qq] = p[qq];
      else v[qq] = float4{0.f, 0.f, 0.f, 0.f};
    }
  };
  auto cvt_write = [&](int buf) {
    char* base = LBUF + buf * 32768 + ssec + wbase;
#pragma unroll
    for (int g = 0; g < 2; ++g) {
      float fs[8] = {v[2*g].x, v[2*g].y, v[2*g].z, v[2*g].w,
                     v[2*g+1].x, v[2*g+1].y, v[2*g+1].z, v[2*g+1].w};
      f16x8 hvv, lvv;
#pragma unroll
      for (int j = 0; j < 8; ++j) {
        _Float16 h16 = (_Float16)fs[j];
        lvv[j] = (_Float16)((fs[j] - (float)h16) * 2048.0f);
        hvv[j] = h16;
      }
      *(f16x8*)(base + g * 256) = hvv;
      *(f16x8*)(base + g * 256 + 4096) = lvv;
    }
  };
  load_regs(0);
  cvt_write(0);
  __syncthreads();
  for (int s = 0; s < nstMax; ++s) {
    const int cur = s & 1, nxt = cur ^ 1;
    const bool doStage = (s + 1 < myNst);
    if (doStage) load_regs(s + 1);
    if (s < waveNst) {
      const char* A0 = LBUF + cur * 32768 + secAr;
      const char* B0 = LBUF + cur * 32768 + secBr;
      f16x8 ah[2], al[2], bh[2], bl[2];
#pragma unroll
      for (int r = 0; r < 2; ++r) {
        ah[r] = *(const f16x8*)(A0 + ((mb + r) << 10) + (lane << 4));
        al[r] = *(const f16x8*)(A0 + 4096 + ((mb + r) << 10) + (lane << 4));
      }
#pragma unroll
      for (int c = 0; c < 2; ++c) {
        bh[c] = *(const f16x8*)(B0 + ((nbb + c) << 10) + (lane << 4));
        bl[c] = *(const f16x8*)(B0 + 4096 + ((nbb + c) << 10) + (lane << 4));
      }
#pragma unroll
      for (int r = 0; r < 2; ++r)
#pragma unroll
        for (int c = 0; c < 2; ++c) {
          int ix = r * 2 + c;
          accH[ix] = __builtin_amdgcn_mfma_f32_16x16x32_f16(ah[r], bh[c], accH[ix], 0, 0, 0);
          accL[ix] = __builtin_amdgcn_mfma_f32_16x16x32_f16(al[r], bh[c], accL[ix], 0, 0, 0);
          accL[ix] = __builtin_amdgcn_mfma_f32_16x16x32_f16(ah[r], bl[c], accL[ix], 0, 0, 0);
        }
    }
    if (doStage) cvt_write(nxt);
    __syncthreads();
  }
  float* GH = (float*)LBUF;
  float* GL = GH + 64 * 68;
  const int mrow0 = ((q >> 1) << 5) + ((lane >> 4) << 2);
  const int ncol0 = ((q & 1) << 5) + (lane & 15);
  if (wHalf == 0) {
#pragma unroll
    for (int r = 0; r < 2; ++r)
#pragma unroll
      for (int c = 0; c < 2; ++c) {
        f32x4 aH = accH[r * 2 + c], aL = accL[r * 2 + c];
        int mr = mrow0 + r * 16, nc = ncol0 + c * 16;
#pragma unroll
        for (int i = 0; i < 4; ++i) { GH[(mr + i) * 68 + nc] = aH[i]; GL[(mr + i) * 68 + nc] = aL[i]; }
      }
  }
  __syncthreads();
  if (wHalf == 1) {
#pragma unroll
    for (int r = 0; r < 2; ++r)
#pragma unroll
      for (int c = 0; c < 2; ++c) {
        f32x4 aH = accH[r * 2 + c], aL = accL[r * 2 + c];
        int mr = mrow0 + r * 16, nc = ncol0 + c * 16;
#pragma unroll
        for (int i = 0; i < 4; ++i) { GH[(mr + i) * 68 + nc] += aH[i]; GL[(mr + i) * 68 + nc] += aL[i]; }
      }
  }
  __syncthreads();
  const float LSC = 1.0f / 2048.0f;
#pragma unroll
  for (int e = 0; e < 2; ++e) {
    int ci = tid * 2 + e;
    int bl_ = ci >> 4, hh = ci & 15;
    int b = m0 + bl_, hcol = h0c + hh;
    float xi = GH[bl_ * 68 + hh]      + GL[bl_ * 68 + hh]      * LSC + bcomb[hcol];
    float xf = GH[bl_ * 68 + 16 + hh] + GL[bl_ * 68 + 16 + hh] * LSC + bcomb[1024 + hcol];
    float xg = GH[bl_ * 68 + 32 + hh] + GL[bl_ * 68 + 32 + hh] * LSC + bcomb[2048 + hcol];
    float xo = GH[bl_ * 68 + 48 + hh] + GL[bl_ * 68 + 48 + hh] * LSC + bcomb[3072 + hcol];
    size_t cidx = (size_t)b * 1024 + hcol;
    float cn = fsig(xf) * cbuf[cidx] + fsig(xi) * ftanhf(xg);
    float hn = fsig(xo) * ftanhf(cn);
    cbuf[cidx] = cn;
    hdst[cidx] = hn;
  }
}

__global__ __launch_bounds__(64) void k_decodeO(
    const float* __restrict__ h2, const float* __restrict__ Wdec,
    const float* __restrict__ bdec, const float* __restrict__ emb,
    float* __restrict__ out, float* __restrict__ ebuf, int t) {
  const int b = blockIdx.x, lane = threadIdx.x;
  const float* hrow = h2 + (size_t)b * 1024;
  float logit = 0.f;
  if (lane < OO) {
    const float* wrow = Wdec + (size_t)lane * 1024;
    float p0 = 0.f, p1 = 0.f, p2 = 0.f, p3 = 0.f;
    for (int k = 0; k < 1024; k += 16) {
      float4 w0 = *(const float4*)(wrow + k);      float4 h0v = *(const float4*)(hrow + k);
      float4 w1 = *(const float4*)(wrow + k + 4);  float4 h1v = *(const float4*)(hrow + k + 4);
      float4 w2 = *(const float4*)(wrow + k + 8);  float4 h2v = *(const float4*)(hrow + k + 8);
      float4 w3 = *(const float4*)(wrow + k + 12); float4 h3v = *(const float4*)(hrow + k + 12);
      p0 += w0.x * h0v.x + w0.y * h0v.y + w0.z * h0v.z + w0.w * h0v.w;
      p1 += w1.x * h1v.x + w1.y * h1v.y + w1.z * h1v.z + w1.w * h1v.w;
      p2 += w2.x * h2v.x + w2.y * h2v.y + w2.z * h2v.z + w2.w * h2v.w;
      p3 += w3.x * h3v.x + w3.y * h3v.y + w3.z * h3v.z + w3.w * h3v.w;
    }
    logit = ((p0 + p1) + (p2 + p3)) + bdec[lane];
  }
  float vv = (lane < OO) ? logit : -3.0e38f;
  int idx = (lane < OO) ? lane : 1000;
#pragma unroll
  for (int m = 1; m < 64; m <<= 1) {
    float v2 = __shfl_xor(vv, m, 64);
    int i2 = __shfl_xor(idx, m, 64);
    if (v2 > vv || (v2 == vv && i2 < idx)) { vv = v2; idx = i2; }
  }
  if (lane < OO) out[(size_t)b * (TT * OO) + t * OO + lane] = logit;
  if (t < TT - 1) {
    const float* erow = emb + (size_t)idx * 1024;
#pragma unroll
    for (int i = 0; i < 16; ++i) {
      int h = i * 64 + lane;
      ebuf[(size_t)b * 1056 + h] = erow[h];
    }
  }
}

__global__ void k_finalO(const float* __restrict__ ws, float* __restrict__ out) {
  int i = blockIdx.x * blockDim.x + threadIdx.x;
  int stride = gridDim.x * blockDim.x;
  const int HBASE = BB * TT * OO;
  for (; i < 2 * 786432; i += stride) {
    if (i < 786432) {
      int l = i >> 18, r = i & 262143;
      out[HBASE + i] = ws[O_HP(l, 0) + r];
    } else {
      int j = i - 786432;
      out[HBASE + 786432 + j] = ws[O_CBUF + j];
    }
  }
}

// ---------------------------------------------------------------------------
extern "C" void kernel_launch(void* const* d_in, const int* in_sizes, int n_in,
                              void* d_out, int out_size, void* d_ws, size_t ws_size,
                              hipStream_t stream) {
  const float* props = (const float*)d_in[1];
  const float* emb   = (const float*)d_in[2];
  const float* Wdec  = (const float*)d_in[3];
  const float* bdec  = (const float*)d_in[4];
  const float* Wih0  = (const float*)d_in[5];
  const float* Wihr  = (const float*)d_in[6];
  const float* Whh   = (const float*)d_in[7];
  const float* bih   = (const float*)d_in[8];
  const float* bhh   = (const float*)d_in[9];
  float* out = (float*)d_out;

  if (ws_size >= (size_t)WS_NEEDED) {
    // ---------------- new pre-split path ----------------
    char* base = (char*)d_ws;
    float* cb = (float*)(base + CBUF_B);
    float* hf = (float*)(base + HF32_B);
    float* bc = (float*)(base + BCOMB_B);
    unsigned short* Ehi = (unsigned short*)(base + EHI_B);
    unsigned short* Elo = (unsigned short*)(base + ELO_B);
    auto HS = [&](int l, int p, int prec) {
      return (unsigned short*)(base + HS_B + (size_t)((l * 2 + p) * 2 + prec) * 524288u);
    };
    // weights: Wx0 hi/lo (33-chunk), then Wh0, Wx1, Wh1, Wx2, Wh2 (32-chunk)
    unsigned short* Wp[12];
    {
      size_t off = W_B;
      Wp[0] = (unsigned short*)(base + off); off += 8650752u;   // Wx0 hi
      Wp[1] = (unsigned short*)(base + off); off += 8650752u;   // Wx0 lo
      for (int i = 2; i < 12; ++i) { Wp[i] = (unsigned short*)(base + off); off += 8388608u; }
      // order: 2,3=Wh0  4,5=Wx1  6,7=Wh1  8,9=Wx2  10,11=Wh2
    }

    k_zero<<<2048, 256, 0, stream>>>((float*)base, 2359296);          // cbuf+hf32
    k_zero<<<2048, 256, 0, stream>>>((float*)(base + HS_B), 1572864); // h split bufs
    k_binit<<<48, 256, 0, stream>>>(bc, bih, bhh);
    k_einit<<<256, 256, 0, stream>>>(Ehi, Elo, emb, props);
    k_prepw<<<4096, 256, 0, stream>>>(Wih0, Wp[0], Wp[1], 1028, 33);
    k_prepw<<<4096, 256, 0, stream>>>(Whh,                          Wp[2], Wp[3], 1024, 32);
    k_prepw<<<4096, 256, 0, stream>>>(Wihr,                         Wp[4], Wp[5], 1024, 32);
    k_prepw<<<4096, 256, 0, stream>>>(Whh + (size_t)4096 * 1024,    Wp[6], Wp[7], 1024, 32);
    k_prepw<<<4096, 256, 0, stream>>>(Wihr + (size_t)4096 * 1024,   Wp[8], Wp[9], 1024, 32);
    k_prepw<<<4096, 256, 0, stream>>>(Whh + (size_t)2 * 4096 * 1024, Wp[10], Wp[11], 1024, 32);

    for (int t = 0; t < TT; ++t) {
      const int p = t & 1, pn = p ^ 1;
      k_layer<<<256, 512, 0, stream>>>(
          (const char*)Ehi, (const char*)Elo, 33,
          (const char*)HS(0, p, 0), (const char*)HS(0, p, 1),
          (const char*)Wp[0], (const char*)Wp[1],
          (const char*)Wp[2], (const char*)Wp[3],
          bc, cb, hf + (size_t)(0 * 2 + pn) * 262144,
          HS(0, pn, 0), HS(0, pn, 1));
      k_layer<<<256, 512, 0, stream>>>(
          (const char*)HS(0, pn, 0), (const char*)HS(0, pn, 1), 32,
          (const char*)HS(1, p, 0), (const char*)HS(1, p, 1),
          (const char*)Wp[4], (const char*)Wp[5],
          (const char*)Wp[6], (const char*)Wp[7],
          bc + 4096, cb + 262144, hf + (size_t)(1 * 2 + pn) * 262144,
          HS(1, pn, 0), HS(1, pn, 1));
      k_layer<<<256, 512, 0, stream>>>(
          (const char*)HS(1, pn, 0), (const char*)HS(1, pn, 1), 32,
          (const char*)HS(2, p, 0), (const char*)HS(2, p, 1),
          (const char*)Wp[8], (const char*)Wp[9],
          (const char*)Wp[10], (const char*)Wp[11],
          bc + 8192, cb + 524288, hf + (size_t)(2 * 2 + pn) * 262144,
          HS(2, pn, 0), HS(2, pn, 1));
      k_decode<<<256, 256, 0, stream>>>(hf + (size_t)(2 * 2 + pn) * 262144,
                                        Wdec, bdec, emb, out, Ehi, Elo, t);
    }
    k_final<<<2048, 256, 0, stream>>>(hf, cb, out);
  } else {
    // ---------------- legacy R4 path ----------------
    float* ws = (float*)d_ws;
    float* E  = ws + O_EBUF;
    float* cb = ws + O_CBUF;
    float* bc = ws + O_BCOMB;
    k_zero<<<2048, 256, 0, stream>>>(ws, O_WSN);
    k_initO<<<1104, 256, 0, stream>>>(ws, props, emb, bih, bhh);
    for (int t = 0; t < TT; ++t) {
      const int p = t & 1;
      k_layerO<<<256, 512, 0, stream>>>(E, 1056, 1028, 33, ws + O_HP(0, p),
                                        Wih0, 1028, Whh, bc, cb, ws + O_HP(0, p ^ 1));
      k_layerO<<<256, 512, 0, stream>>>(ws + O_HP(0, p ^ 1), 1024, 1024, 32,
                                        ws + O_HP(1, p), Wihr, 1024,
                                        Whh + (size_t)4096 * 1024,
                                        bc + 4096, cb + 262144, ws + O_HP(1, p ^ 1));
      k_layerO<<<256, 512, 0, stream>>>(ws + O_HP(1, p ^ 1), 1024, 1024, 32,
                                        ws + O_HP(2, p),
                                        Wihr + (size_t)4096 * 1024, 1024,
                                        Whh + (size_t)2 * 4096 * 1024,
                                        bc + 8192, cb + 524288, ws + O_HP(2, p ^ 1));
      k_decodeO<<<256, 64, 0, stream>>>(ws + O_HP(2, p ^ 1), Wdec, bdec, emb, out, E, t);
    }
    k_finalO<<<2048, 256, 0, stream>>>(ws, out);
  }
}

// Round 6
// 10441.518 us; speedup vs baseline: 3.8547x; 1.0729x over previous
//
#include <hip/hip_runtime.h>
#include <hip/hip_bf16.h>
#include <cstdint>
#include <cstddef>

// ---------------------------------------------------------------------------
// ConditionalSmilesRnn: 3-layer LSTM, H=1024, B=256, T=128, greedy decode.
// Round 6: fp16x3 split MFMA GEMM, pre-split/pre-swizzled operands, and a
// DEPTH-4 COUNTED-VMCNT PIPELINE (raw s_barrier + s_waitcnt vmcnt(N)) so
// global_load_lds prefetches stay in flight across barriers (T3/T4).
//   - per chunk: vmcnt(12) -> barrier -> ds_read+12 MFMA -> lgkmcnt(0)
//     -> barrier -> stage(s+4) into freed buffer
//   - ping-pong h buffers (race fix) retained; legacy R4 fallback retained
// ---------------------------------------------------------------------------

#define BB 256
#define TT 128
#define OO 47

typedef __attribute__((ext_vector_type(8))) _Float16 f16x8;
typedef __attribute__((ext_vector_type(4))) float f32x4;

// ---- new-path workspace byte offsets ----
#define CBUF_B   0u                    // [3][256][1024] f32
#define HF32_B   3145728u              // [3][2][256][1024] f32
#define BCOMB_B  9437184u              // [3][4096] f32
#define EHI_B    9486336u              // [16][33][512] f16 slabs
#define ELO_B    10027008u
#define HS_B     10567680u             // [3][2][2]: 16*32*1024 B each
#define W_B      16859136u
#define WS_NEEDED 118046720u

#define BARRIER() asm volatile("s_barrier" ::: "memory")
#define WAITV(n)  asm volatile("s_waitcnt vmcnt(" #n ")" ::: "memory")
#define WAITLGKM0() asm volatile("s_waitcnt lgkmcnt(0)" ::: "memory")

__device__ __forceinline__ float fsig(float x) {
  return 1.0f / (1.0f + exp2f(-1.4426950408889634f * x));
}
__device__ __forceinline__ float ftanhf(float x) {
  float e = exp2f(2.8853900817779268f * x);
  return 1.0f - 2.0f / (e + 1.0f);
}
__device__ __forceinline__ unsigned short f16b(_Float16 h) {
  union { _Float16 f; unsigned short u; } c; c.f = h; return c.u;
}
__device__ __forceinline__ void gld16(const void* g, void* l) {
  __builtin_amdgcn_global_load_lds(
      (const __attribute__((address_space(1))) unsigned int*)g,
      (__attribute__((address_space(3))) unsigned int*)l, 16, 0, 0);
}
// slab address (in f16 units) for element (row-in-16-group r, k) of group grp
__device__ __forceinline__ size_t slab_addr(int grp, int NCH, int k, int r) {
  return ((size_t)grp * NCH + (k >> 5)) * 512 + ((k >> 4) & 1) * 256 +
         ((k >> 3) & 1) * 128 + r * 8 + (k & 7);
}

// ---------------------------------------------------------------------------
__global__ void k_zero(float* p, int n) {
  int i = blockIdx.x * blockDim.x + threadIdx.x;
  int stride = gridDim.x * blockDim.x;
  for (; i < n; i += stride) p[i] = 0.0f;
}

__global__ void k_binit(float* bc, const float* __restrict__ bih,
                        const float* __restrict__ bhh) {
  int i = blockIdx.x * blockDim.x + threadIdx.x;
  if (i < 12288) bc[i] = bih[i] + bhh[i];
}

// split fp32 weight matrix [4096][K] into slab-ordered f16 hi/lo (zero pad)
__global__ void k_prepw(const float* __restrict__ src, unsigned short* dhi,
                        unsigned short* dlo, int K, int NCH) {
  const int nrow = blockIdx.x;
  const int ngrp = nrow >> 4, rr = nrow & 15;
  const float* s = src + (size_t)nrow * K;
  for (int k = threadIdx.x; k < NCH * 32; k += blockDim.x) {
    float val = (k < K) ? s[k] : 0.0f;
    _Float16 h16 = (_Float16)val;
    _Float16 l16 = (_Float16)((val - (float)h16) * 2048.0f);
    size_t a = slab_addr(ngrp, NCH, k, rr);
    dhi[a] = f16b(h16);
    dlo[a] = f16b(l16);
  }
}

// E = [emb(tok 0) | props | pad] split into slabs (NCH=33)
__global__ void k_einit(unsigned short* ehi, unsigned short* elo,
                        const float* __restrict__ emb,
                        const float* __restrict__ props) {
  const int b = blockIdx.x;
  for (int j = threadIdx.x; j < 1056; j += blockDim.x) {
    float val = (j < 1024) ? emb[j] : (j < 1028 ? props[b * 4 + (j - 1024)] : 0.0f);
    _Float16 h16 = (_Float16)val;
    _Float16 l16 = (_Float16)((val - (float)h16) * 2048.0f);
    size_t a = slab_addr(b >> 4, 33, j, b & 15);
    ehi[a] = f16b(h16);
    elo[a] = f16b(l16);
  }
}

// ---------------------------------------------------------------------------
// fp16x3 MFMA fused GEMM+LSTM cell, pre-split operands, depth-4 pipeline.
// grid 256 (4 batch x 64 h tiles, XCD-swizzled), 512 threads (8 waves).
// LDS: 4 buffers x 32KB; buffer layout [isB][half][prec][slab4][1024B].
// Staging: wave w -> isB=w>>2, half=(w>>1)&1, prec=w&1, 4 slab copies/chunk.
// Compute: wave w -> wHalf=w>>2, quadrant q=w&3 (32x32 of the 64x64 tile).
__global__ __launch_bounds__(512, 2) void k_layer(
    const char* __restrict__ xhi, const char* __restrict__ xlo, int NCHX,
    const char* __restrict__ hhi, const char* __restrict__ hlo,
    const char* __restrict__ wxhi, const char* __restrict__ wxlo,
    const char* __restrict__ whhi, const char* __restrict__ whlo,
    const float* __restrict__ bcomb, float* __restrict__ cbuf,
    float* __restrict__ hdstf, unsigned short* __restrict__ hshi,
    unsigned short* __restrict__ hslo) {
  __shared__ char LBUF[131072];
  const int tid = threadIdx.x;
  const int lane = tid & 63, wid = tid >> 6;
  const int sw = ((blockIdx.x & 7) << 5) + (blockIdx.x >> 3);  // XCD swizzle
  const int mt = sw & 3, nt = sw >> 2;
  const int m0 = mt << 6, h0c = nt << 4;
  const int nst = (NCHX > 32) ? NCHX : 32;

  // ---- staging role ----
  const int sIsB = wid >> 2, sHalfW = (wid >> 1) & 1, sPrec = wid & 1;
  const int sNch = sHalfW ? 32 : NCHX;
  const char* sbase[4];
  {
    const char* t0;
    if (!sIsB) t0 = sHalfW ? (sPrec ? hlo : hhi) : (sPrec ? xlo : xhi);
    else       t0 = sHalfW ? (sPrec ? whlo : whhi) : (sPrec ? wxlo : wxhi);
#pragma unroll
    for (int i = 0; i < 4; ++i) {
      int grp = sIsB ? (i * 64 + nt) : (mt * 4 + i);
      sbase[i] = t0 + (size_t)grp * sNch * 1024 + (size_t)lane * 16;
    }
  }
  const int ldsoff0 = (sIsB << 14) + (sHalfW << 13) + (sPrec << 12);
  auto stage = [&](int s, int buf) {
    char* ldst = LBUF + buf * 32768 + ldsoff0;
    const size_t so = (size_t)s * 1024;
#pragma unroll
    for (int i = 0; i < 4; ++i) gld16(sbase[i] + so, ldst + i * 1024);
  };

  // ---- compute role ----
  const int wHalf = wid >> 2, q = wid & 3;
  const int mb = (q >> 1) << 1, nbb = (q & 1) << 1;
  const int waveNst = wHalf ? 32 : NCHX;

  f32x4 accH[4], accL[4];
#pragma unroll
  for (int i = 0; i < 4; ++i) {
    accH[i] = f32x4{0.f, 0.f, 0.f, 0.f};
    accL[i] = f32x4{0.f, 0.f, 0.f, 0.f};
  }

  // prologue: fill 4 buffers (sNch >= 32 > 4 always)
  stage(0, 0);
  stage(1, 1);
  stage(2, 2);
  stage(3, 3);

  for (int s = 0; s < nst; ++s) {
    const int buf = s & 3;
    // wait until this wave's chunk-s loads have landed (counted, per-wave)
    if (s + 3 < sNch)      { WAITV(12); }
    else if (s + 2 < sNch) { WAITV(8); }
    else if (s + 1 < sNch) { WAITV(4); }
    else                   { WAITV(0); }
    BARRIER();                       // all waves' chunk-s data now in LDS

    if (s < waveNst) {
      const char* A0 = LBUF + buf * 32768 + (wHalf << 13);
      const char* B0 = LBUF + buf * 32768 + 16384 + (wHalf << 13);
      f16x8 ah[2], al[2], bh[2], bl[2];
#pragma unroll
      for (int r = 0; r < 2; ++r) {
        ah[r] = *(const f16x8*)(A0 + ((mb + r) << 10) + (lane << 4));
        al[r] = *(const f16x8*)(A0 + 4096 + ((mb + r) << 10) + (lane << 4));
      }
#pragma unroll
      for (int c = 0; c < 2; ++c) {
        bh[c] = *(const f16x8*)(B0 + ((nbb + c) << 10) + (lane << 4));
        bl[c] = *(const f16x8*)(B0 + 4096 + ((nbb + c) << 10) + (lane << 4));
      }
#pragma unroll
      for (int r = 0; r < 2; ++r)
#pragma unroll
        for (int c = 0; c < 2; ++c) {
          int ix = r * 2 + c;
          accH[ix] = __builtin_amdgcn_mfma_f32_16x16x32_f16(ah[r], bh[c], accH[ix], 0, 0, 0);
          accL[ix] = __builtin_amdgcn_mfma_f32_16x16x32_f16(al[r], bh[c], accL[ix], 0, 0, 0);
          accL[ix] = __builtin_amdgcn_mfma_f32_16x16x32_f16(ah[r], bl[c], accL[ix], 0, 0, 0);
        }
    }

    WAITLGKM0();                     // this wave's ds_reads complete
    BARRIER();                       // all waves done reading buf
    if (s + 4 < sNch) stage(s + 4, buf);   // refill freed buffer (async)
  }

  // ---- epilogue: combine halves, fused LSTM cell, split h emit ----
  BARRIER();
  float* GH = (float*)LBUF;            // [64][68]
  float* GL = GH + 64 * 68;
  const int mrow0 = ((q >> 1) << 5) + ((lane >> 4) << 2);
  const int ncol0 = ((q & 1) << 5) + (lane & 15);
  if (wHalf == 0) {
#pragma unroll
    for (int r = 0; r < 2; ++r)
#pragma unroll
      for (int c = 0; c < 2; ++c) {
        f32x4 aH = accH[r * 2 + c], aL = accL[r * 2 + c];
        int mr = mrow0 + r * 16, nc = ncol0 + c * 16;
#pragma unroll
        for (int i = 0; i < 4; ++i) {
          GH[(mr + i) * 68 + nc] = aH[i];
          GL[(mr + i) * 68 + nc] = aL[i];
        }
      }
  }
  __syncthreads();
  if (wHalf == 1) {
#pragma unroll
    for (int r = 0; r < 2; ++r)
#pragma unroll
      for (int c = 0; c < 2; ++c) {
        f32x4 aH = accH[r * 2 + c], aL = accL[r * 2 + c];
        int mr = mrow0 + r * 16, nc = ncol0 + c * 16;
#pragma unroll
        for (int i = 0; i < 4; ++i) {
          GH[(mr + i) * 68 + nc] += aH[i];
          GL[(mr + i) * 68 + nc] += aL[i];
        }
      }
  }
  __syncthreads();

  const float LSC = 1.0f / 2048.0f;
#pragma unroll
  for (int e = 0; e < 2; ++e) {
    int ci = tid * 2 + e;           // 0..1023
    int bl_ = ci >> 4, hh = ci & 15;
    int b = m0 + bl_, hcol = h0c + hh;
    float xi = GH[bl_ * 68 + hh]      + GL[bl_ * 68 + hh]      * LSC + bcomb[hcol];
    float xf = GH[bl_ * 68 + 16 + hh] + GL[bl_ * 68 + 16 + hh] * LSC + bcomb[1024 + hcol];
    float xg = GH[bl_ * 68 + 32 + hh] + GL[bl_ * 68 + 32 + hh] * LSC + bcomb[2048 + hcol];
    float xo = GH[bl_ * 68 + 48 + hh] + GL[bl_ * 68 + 48 + hh] * LSC + bcomb[3072 + hcol];
    size_t cidx = (size_t)b * 1024 + hcol;
    float cn = fsig(xf) * cbuf[cidx] + fsig(xi) * ftanhf(xg);
    float hn = fsig(xo) * ftanhf(cn);
    cbuf[cidx] = cn;
    hdstf[cidx] = hn;
    _Float16 h16 = (_Float16)hn;
    _Float16 l16 = (_Float16)((hn - (float)h16) * 2048.0f);
    size_t sa = slab_addr(b >> 4, 32, hcol, b & 15);
    hshi[sa] = f16b(h16);
    hslo[sa] = f16b(l16);
  }
}

// ---------------------------------------------------------------------------
// decode: 4-wave k-split dot, argmax, emit next-token emb into E slabs
__global__ __launch_bounds__(256) void k_decode(
    const float* __restrict__ h2, const float* __restrict__ Wdec,
    const float* __restrict__ bdec, const float* __restrict__ emb,
    float* __restrict__ out, unsigned short* __restrict__ ehi,
    unsigned short* __restrict__ elo, int t) {
  __shared__ float P[4][64];
  __shared__ int tokS;
  const int b = blockIdx.x;
  const int w = threadIdx.x >> 6, lane = threadIdx.x & 63;
  const float* hrow = h2 + (size_t)b * 1024 + w * 256;
  float part = 0.f;
  if (lane < OO) {
    const float* wrow = Wdec + (size_t)lane * 1024 + w * 256;
    float p0 = 0.f, p1 = 0.f, p2 = 0.f, p3 = 0.f;
    for (int k = 0; k < 256; k += 16) {
      float4 w0 = *(const float4*)(wrow + k);      float4 h0v = *(const float4*)(hrow + k);
      float4 w1 = *(const float4*)(wrow + k + 4);  float4 h1v = *(const float4*)(hrow + k + 4);
      float4 w2 = *(const float4*)(wrow + k + 8);  float4 h2v = *(const float4*)(hrow + k + 8);
      float4 w3 = *(const float4*)(wrow + k + 12); float4 h3v = *(const float4*)(hrow + k + 12);
      p0 += w0.x * h0v.x + w0.y * h0v.y + w0.z * h0v.z + w0.w * h0v.w;
      p1 += w1.x * h1v.x + w1.y * h1v.y + w1.z * h1v.z + w1.w * h1v.w;
      p2 += w2.x * h2v.x + w2.y * h2v.y + w2.z * h2v.z + w2.w * h2v.w;
      p3 += w3.x * h3v.x + w3.y * h3v.y + w3.z * h3v.z + w3.w * h3v.w;
    }
    part = (p0 + p1) + (p2 + p3);
  }
  P[w][lane] = part;
  __syncthreads();
  if (w == 0) {
    float logit = -3.0e38f;
    if (lane < OO)
      logit = P[0][lane] + P[1][lane] + P[2][lane] + P[3][lane] + bdec[lane];
    float vv = logit;
    int idx = (lane < OO) ? lane : 1000;
#pragma unroll
    for (int m = 1; m < 64; m <<= 1) {
      float v2 = __shfl_xor(vv, m, 64);
      int i2 = __shfl_xor(idx, m, 64);
      if (v2 > vv || (v2 == vv && i2 < idx)) { vv = v2; idx = i2; }
    }
    if (lane < OO) out[(size_t)b * (TT * OO) + t * OO + lane] = logit;
    if (lane == 0) tokS = idx;
  }
  __syncthreads();
  if (t < TT - 1) {
    const float* erow = emb + (size_t)tokS * 1024;
    float4 ev = ((const float4*)erow)[threadIdx.x];
    float vals[4] = {ev.x, ev.y, ev.z, ev.w};
#pragma unroll
    for (int r = 0; r < 4; ++r) {
      int j = threadIdx.x * 4 + r;
      _Float16 h16 = (_Float16)vals[r];
      _Float16 l16 = (_Float16)((vals[r] - (float)h16) * 2048.0f);
      size_t a = slab_addr(b >> 4, 33, j, b & 15);
      ehi[a] = f16b(h16);
      elo[a] = f16b(l16);
    }
  }
}

// ---------------------------------------------------------------------------
__global__ void k_final(const float* __restrict__ hf, const float* __restrict__ cb,
                        float* __restrict__ out) {
  int i = blockIdx.x * blockDim.x + threadIdx.x;
  int stride = gridDim.x * blockDim.x;
  const int HBASE = BB * TT * OO;   // 1540096
  for (; i < 2 * 786432; i += stride) {
    if (i < 786432) {               // h [L][B][H]; final state in parity 0
      int l = i >> 18, r = i & 262143;
      out[HBASE + i] = hf[(size_t)(l * 2 + 0) * 262144 + r];
    } else {
      int j = i - 786432;
      out[HBASE + 786432 + j] = cb[j];
    }
  }
}

// ===========================================================================
// ==================== LEGACY (R4) FALLBACK PATH ============================
// ===========================================================================
#define O_EBUF  0
#define O_HPB   270336
#define O_CBUF  1843200
#define O_BCOMB 2629632
#define O_WSN   2641920
#define O_HP(l, p) (O_HPB + ((l) * 2 + (p)) * 262144)

__global__ void k_initO(float* ws, const float* __restrict__ props,
                        const float* __restrict__ emb,
                        const float* __restrict__ bih,
                        const float* __restrict__ bhh) {
  int i = blockIdx.x * blockDim.x + threadIdx.x;
  if (i < 270336) {
    int b = i / 1056, j = i % 1056;
    float v = 0.0f;
    if (j < 1024) v = emb[j];
    else if (j < 1028) v = props[b * 4 + (j - 1024)];
    ws[O_EBUF + i] = v;
  } else if (i < 270336 + 12288) {
    int j = i - 270336;
    ws[O_BCOMB + j] = bih[j] + bhh[j];
  }
}

__global__ __launch_bounds__(512, 2) void k_layerO(
    const float* __restrict__ xsrc, int xs, int Kx, int nst0,
    const float* __restrict__ hsrc,
    const float* __restrict__ Wx, int wxs,
    const float* __restrict__ Wh,
    const float* __restrict__ bcomb, float* __restrict__ cbuf,
    float* __restrict__ hdst) {
  __shared__ char LBUF[65536];
  const int tid = threadIdx.x;
  const int lane = tid & 63, wid = tid >> 6;
  const int sw = ((blockIdx.x & 7) << 5) + (blockIdx.x >> 3);
  const int mt = sw & 3, nt = sw >> 2;
  const int m0 = mt << 6, h0c = nt << 4;
  const int nstMax = (nst0 > 32) ? nst0 : 32;
  const int tile = tid >> 7;
  const int tt = tid & 127;
  const int srow = tt >> 1;
  const int kseg = (tt & 1) << 4;
  const int isB = tile >> 1, sHalf = tile & 1;
  const int myNst = sHalf ? 32 : nst0;
  const float* grow;
  int KactB = 0x7fffffff;
  if (!isB) {
    grow = sHalf ? (hsrc + (size_t)(m0 + srow) * 1024)
                 : (xsrc + (size_t)(m0 + srow) * xs);
  } else {
    int nrow = ((srow >> 4) << 10) + h0c + (srow & 15);
    grow = sHalf ? (Wh + (size_t)nrow * 1024) : (Wx + (size_t)nrow * wxs);
    KactB = sHalf ? 1024 : Kx;
  }
  const int wbase = ((srow >> 4) << 10) + ((tt & 1) << 9) + ((srow & 15) << 4);
  const int ssec = (isB << 14) + (sHalf << 13);
  const int wHalf = wid >> 2, q = wid & 3;
  const int mb = (q >> 1) << 1, nbb = (q & 1) << 1;
  const int waveNst = wHalf ? 32 : nst0;
  const int secAr = (wHalf << 13);
  const int secBr = 16384 + (wHalf << 13);
  f32x4 accH[4], accL[4];
#pragma unroll
  for (int i = 0; i < 4; ++i) {
    accH[i] = f32x4{0.f, 0.f, 0.f, 0.f};
    accL[i] = f32x4{0.f, 0.f, 0.f, 0.f};
  }
  float4 v[4];
  auto load_regs = [&](int s) {
    const int kl = (s << 5) + kseg;
    const float4* p = (const float4*)(grow + kl);
#pragma unroll
    for (int qq = 0; qq < 4; ++qq) {
      int kk = kl + qq * 4;
      if (kk < KactB) v[qq] = p[qq];
      else v[qq] = float4{0.f, 0.f, 0.f, 0.f};
    }
  };
  auto cvt_write = [&](int buf) {
    char* base = LBUF + buf * 32768 + ssec + wbase;
#pragma unroll
    for (int g = 0; g < 2; ++g) {
      float fs[8] = {v[2*g].x, v[2*g].y, v[2*g].z, v[2*g].w,
                     v[2*g+1].x, v[2*g+1].y, v[2*g+1].z, v[2*g+1].w};
      f16x8 hvv, lvv;
#pragma unroll
      for (int j = 0; j < 8; ++j) {
        _Float16 h16 = (_Float16)fs[j];
        lvv[j] = (_Float16)((fs[j] - (float)h16) * 2048.0f);
        hvv[j] = h16;
      }
      *(f16x8*)(base + g * 256) = hvv;
      *(f16x8*)(base + g * 256 + 4096) = lvv;
    }
  };
  load_regs(0);
  cvt_write(0);
  __syncthreads();
  for (int s = 0; s < nstMax; ++s) {
    const int cur = s & 1, nxt = cur ^ 1;
    const bool doStage = (s + 1 < myNst);
    if (doStage) load_regs(s + 1);
    if (s < waveNst) {
      const char* A0 = LBUF + cur * 32768 + secAr;
      const char* B0 = LBUF + cur * 32768 + secBr;
      f16x8 ah[2], al[2], bh[2], bl[2];
#pragma unroll
      for (int r = 0; r < 2; ++r) {
        ah[r] = *(const f16x8*)(A0 + ((mb + r) << 10) + (lane << 4));
        al[r] = *(const f16x8*)(A0 + 4096 + ((mb + r) << 10) + (lane << 4));
      }
#pragma unroll
      for (int c = 0; c < 2; ++c) {
        bh[c] = *(const f16x8*)(B0 + ((nbb + c) << 10) + (lane << 4));
        bl[c] = *(const f16x8*)(B0 + 4096 + ((nbb + c) << 10) + (lane << 4));
      }
#pragma unroll
      for (int r = 0; r < 2; ++r)
#pragma unroll
        for (int c = 0; c < 2; ++c) {
          int ix = r * 2 + c;
          accH[ix] = __builtin_amdgcn_mfma_f32_16x16x32_f16(ah[r], bh[c], accH[ix], 0, 0, 0);
          accL[ix] = __builtin_amdgcn_mfma_f32_16x16x32_f16(al[r], bh[c], accL[ix], 0, 0, 0);
          accL[ix] = __builtin_amdgcn_mfma_f32_16x16x32_f16(ah[r], bl[c], accL[ix], 0, 0, 0);
        }
    }
    if (doStage) cvt_write(nxt);
    __syncthreads();
  }
  float* GH = (float*)LBUF;
  float* GL = GH + 64 * 68;
  const int mrow0 = ((q >> 1) << 5) + ((lane >> 4) << 2);
  const int ncol0 = ((q & 1) << 5) + (lane & 15);
  if (wHalf == 0) {
#pragma unroll
    for (int r = 0; r < 2; ++r)
#pragma unroll
      for (int c = 0; c < 2; ++c) {
        f32x4 aH = accH[r * 2 + c], aL = accL[r * 2 + c];
        int mr = mrow0 + r * 16, nc = ncol0 + c * 16;
#pragma unroll
        for (int i = 0; i < 4; ++i) { GH[(mr + i) * 68 + nc] = aH[i]; GL[(mr + i) * 68 + nc] = aL[i]; }
      }
  }
  __syncthreads();
  if (wHalf == 1) {
#pragma unroll
    for (int r = 0; r < 2; ++r)
#pragma unroll
      for (int c = 0; c < 2; ++c) {
        f32x4 aH = accH[r * 2 + c], aL = accL[r * 2 + c];
        int mr = mrow0 + r * 16, nc = ncol0 + c * 16;
#pragma unroll
        for (int i = 0; i < 4; ++i) { GH[(mr + i) * 68 + nc] += aH[i]; GL[(mr + i) * 68 + nc] += aL[i]; }
      }
  }
  __syncthreads();
  const float LSC = 1.0f / 2048.0f;
#pragma unroll
  for (int e = 0; e < 2; ++e) {
    int ci = tid * 2 + e;
    int bl_ = ci >> 4, hh = ci & 15;
    int b = m0 + bl_, hcol = h0c + hh;
    float xi = GH[bl_ * 68 + hh]      + GL[bl_ * 68 + hh]      * LSC + bcomb[hcol];
    float xf = GH[bl_ * 68 + 16 + hh] + GL[bl_ * 68 + 16 + hh] * LSC + bcomb[1024 + hcol];
    float xg = GH[bl_ * 68 + 32 + hh] + GL[bl_ * 68 + 32 + hh] * LSC + bcomb[2048 + hcol];
    float xo = GH[bl_ * 68 + 48 + hh] + GL[bl_ * 68 + 48 + hh] * LSC + bcomb[3072 + hcol];
    size_t cidx = (size_t)b * 1024 + hcol;
    float cn = fsig(xf) * cbuf[cidx] + fsig(xi) * ftanhf(xg);
    float hn = fsig(xo) * ftanhf(cn);
    cbuf[cidx] = cn;
    hdst[cidx] = hn;
  }
}

__global__ __launch_bounds__(64) void k_decodeO(
    const float* __restrict__ h2, const float* __restrict__ Wdec,
    const float* __restrict__ bdec, const float* __restrict__ emb,
    float* __restrict__ out, float* __restrict__ ebuf, int t) {
  const int b = blockIdx.x, lane = threadIdx.x;
  const float* hrow = h2 + (size_t)b * 1024;
  float logit = 0.f;
  if (lane < OO) {
    const float* wrow = Wdec + (size_t)lane * 1024;
    float p0 = 0.f, p1 = 0.f, p2 = 0.f, p3 = 0.f;
    for (int k = 0; k < 1024; k += 16) {
      float4 w0 = *(const float4*)(wrow + k);      float4 h0v = *(const float4*)(hrow + k);
      float4 w1 = *(const float4*)(wrow + k + 4);  float4 h1v = *(const float4*)(hrow + k + 4);
      float4 w2 = *(const float4*)(wrow + k + 8);  float4 h2v = *(const float4*)(hrow + k + 8);
      float4 w3 = *(const float4*)(wrow + k + 12); float4 h3v = *(const float4*)(hrow + k + 12);
      p0 += w0.x * h0v.x + w0.y * h0v.y + w0.z * h0v.z + w0.w * h0v.w;
      p1 += w1.x * h1v.x + w1.y * h1v.y + w1.z * h1v.z + w1.w * h1v.w;
      p2 += w2.x * h2v.x + w2.y * h2v.y + w2.z * h2v.z + w2.w * h2v.w;
      p3 += w3.x * h3v.x + w3.y * h3v.y + w3.z * h3v.z + w3.w * h3v.w;
    }
    logit = ((p0 + p1) + (p2 + p3)) + bdec[lane];
  }
  float vv = (lane < OO) ? logit : -3.0e38f;
  int idx = (lane < OO) ? lane : 1000;
#pragma unroll
  for (int m = 1; m < 64; m <<= 1) {
    float v2 = __shfl_xor(vv, m, 64);
    int i2 = __shfl_xor(idx, m, 64);
    if (v2 > vv || (v2 == vv && i2 < idx)) { vv = v2; idx = i2; }
  }
  if (lane < OO) out[(size_t)b * (TT * OO) + t * OO + lane] = logit;
  if (t < TT - 1) {
    const float* erow = emb + (size_t)idx * 1024;
#pragma unroll
    for (int i = 0; i < 16; ++i) {
      int h = i * 64 + lane;
      ebuf[(size_t)b * 1056 + h] = erow[h];
    }
  }
}

__global__ void k_finalO(const float* __restrict__ ws, float* __restrict__ out) {
  int i = blockIdx.x * blockDim.x + threadIdx.x;
  int stride = gridDim.x * blockDim.x;
  const int HBASE = BB * TT * OO;
  for (; i < 2 * 786432; i += stride) {
    if (i < 786432) {
      int l = i >> 18, r = i & 262143;
      out[HBASE + i] = ws[O_HP(l, 0) + r];
    } else {
      int j = i - 786432;
      out[HBASE + 786432 + j] = ws[O_CBUF + j];
    }
  }
}

// ---------------------------------------------------------------------------
extern "C" void kernel_launch(void* const* d_in, const int* in_sizes, int n_in,
                              void* d_out, int out_size, void* d_ws, size_t ws_size,
                              hipStream_t stream) {
  const float* props = (const float*)d_in[1];
  const float* emb   = (const float*)d_in[2];
  const float* Wdec  = (const float*)d_in[3];
  const float* bdec  = (const float*)d_in[4];
  const float* Wih0  = (const float*)d_in[5];
  const float* Wihr  = (const float*)d_in[6];
  const float* Whh   = (const float*)d_in[7];
  const float* bih   = (const float*)d_in[8];
  const float* bhh   = (const float*)d_in[9];
  float* out = (float*)d_out;

  if (ws_size >= (size_t)WS_NEEDED) {
    // ---------------- new pre-split path ----------------
    char* base = (char*)d_ws;
    float* cb = (float*)(base + CBUF_B);
    float* hf = (float*)(base + HF32_B);
    float* bc = (float*)(base + BCOMB_B);
    unsigned short* Ehi = (unsigned short*)(base + EHI_B);
    unsigned short* Elo = (unsigned short*)(base + ELO_B);
    auto HS = [&](int l, int p, int prec) {
      return (unsigned short*)(base + HS_B + (size_t)((l * 2 + p) * 2 + prec) * 524288u);
    };
    // weights: Wx0 hi/lo (33-chunk), then Wh0, Wx1, Wh1, Wx2, Wh2 (32-chunk)
    unsigned short* Wp[12];
    {
      size_t off = W_B;
      Wp[0] = (unsigned short*)(base + off); off += 8650752u;   // Wx0 hi
      Wp[1] = (unsigned short*)(base + off); off += 8650752u;   // Wx0 lo
      for (int i = 2; i < 12; ++i) { Wp[i] = (unsigned short*)(base + off); off += 8388608u; }
      // order: 2,3=Wh0  4,5=Wx1  6,7=Wh1  8,9=Wx2  10,11=Wh2
    }

    k_zero<<<2048, 256, 0, stream>>>((float*)base, 2359296);          // cbuf+hf32
    k_zero<<<2048, 256, 0, stream>>>((float*)(base + HS_B), 1572864); // h split bufs
    k_binit<<<48, 256, 0, stream>>>(bc, bih, bhh);
    k_einit<<<256, 256, 0, stream>>>(Ehi, Elo, emb, props);
    k_prepw<<<4096, 256, 0, stream>>>(Wih0, Wp[0], Wp[1], 1028, 33);
    k_prepw<<<4096, 256, 0, stream>>>(Whh,                          Wp[2], Wp[3], 1024, 32);
    k_prepw<<<4096, 256, 0, stream>>>(Wihr,                         Wp[4], Wp[5], 1024, 32);
    k_prepw<<<4096, 256, 0, stream>>>(Whh + (size_t)4096 * 1024,    Wp[6], Wp[7], 1024, 32);
    k_prepw<<<4096, 256, 0, stream>>>(Wihr + (size_t)4096 * 1024,   Wp[8], Wp[9], 1024, 32);
    k_prepw<<<4096, 256, 0, stream>>>(Whh + (size_t)2 * 4096 * 1024, Wp[10], Wp[11], 1024, 32);

    for (int t = 0; t < TT; ++t) {
      const int p = t & 1, pn = p ^ 1;
      k_layer<<<256, 512, 0, stream>>>(
          (const char*)Ehi, (const char*)Elo, 33,
          (const char*)HS(0, p, 0), (const char*)HS(0, p, 1),
          (const char*)Wp[0], (const char*)Wp[1],
          (const char*)Wp[2], (const char*)Wp[3],
          bc, cb, hf + (size_t)(0 * 2 + pn) * 262144,
          HS(0, pn, 0), HS(0, pn, 1));
      k_layer<<<256, 512, 0, stream>>>(
          (const char*)HS(0, pn, 0), (const char*)HS(0, pn, 1), 32,
          (const char*)HS(1, p, 0), (const char*)HS(1, p, 1),
          (const char*)Wp[4], (const char*)Wp[5],
          (const char*)Wp[6], (const char*)Wp[7],
          bc + 4096, cb + 262144, hf + (size_t)(1 * 2 + pn) * 262144,
          HS(1, pn, 0), HS(1, pn, 1));
      k_layer<<<256, 512, 0, stream>>>(
          (const char*)HS(1, pn, 0), (const char*)HS(1, pn, 1), 32,
          (const char*)HS(2, p, 0), (const char*)HS(2, p, 1),
          (const char*)Wp[8], (const char*)Wp[9],
          (const char*)Wp[10], (const char*)Wp[11],
          bc + 8192, cb + 524288, hf + (size_t)(2 * 2 + pn) * 262144,
          HS(2, pn, 0), HS(2, pn, 1));
      k_decode<<<256, 256, 0, stream>>>(hf + (size_t)(2 * 2 + pn) * 262144,
                                        Wdec, bdec, emb, out, Ehi, Elo, t);
    }
    k_final<<<2048, 256, 0, stream>>>(hf, cb, out);
  } else {
    // ---------------- legacy R4 path ----------------
    float* ws = (float*)d_ws;
    float* E  = ws + O_EBUF;
    float* cb = ws + O_CBUF;
    float* bc = ws + O_BCOMB;
    k_zero<<<2048, 256, 0, stream>>>(ws, O_WSN);
    k_initO<<<1104, 256, 0, stream>>>(ws, props, emb, bih, bhh);
    for (int t = 0; t < TT; ++t) {
      const int p = t & 1;
      k_layerO<<<256, 512, 0, stream>>>(E, 1056, 1028, 33, ws + O_HP(0, p),
                                        Wih0, 1028, Whh, bc, cb, ws + O_HP(0, p ^ 1));
      k_layerO<<<256, 512, 0, stream>>>(ws + O_HP(0, p ^ 1), 1024, 1024, 32,
                                        ws + O_HP(1, p), Wihr, 1024,
                                        Whh + (size_t)4096 * 1024,
                                        bc + 4096, cb + 262144, ws + O_HP(1, p ^ 1));
      k_layerO<<<256, 512, 0, stream>>>(ws + O_HP(1, p ^ 1), 1024, 1024, 32,
                                        ws + O_HP(2, p),
                                        Wihr + (size_t)4096 * 1024, 1024,
                                        Whh + (size_t)2 * 4096 * 1024,
                                        bc + 8192, cb + 524288, ws + O_HP(2, p ^ 1));
      k_decodeO<<<256, 64, 0, stream>>>(ws + O_HP(2, p ^ 1), Wdec, bdec, emb, out, E, t);
    }
    k_finalO<<<2048, 256, 0, stream>>>(ws, out);
  }
}